// Round 1
// baseline (85.231 us; speedup 1.0000x reference)
//
#include <hip/hip_runtime.h>

// ConvTranspose4d: temporal valid conv (KT=3) of ConvTranspose3d(stride 2, pad 1, k=3).
// Gather form: out[co,f,od,oh,ow] = sum_{i,ci,kd,kh,kw} x[ci,f+i,id,ih,iw] * W[ci,co,i,kd,kh,kw]
//   where id=(od+1-kd)/2 valid iff parity matches (all parity-valid taps in range).
// Even coord -> 1 tap (k=1); odd coord -> 2 taps (k=0,2). No bounds checks needed.

typedef float f4u __attribute__((ext_vector_type(4), aligned(4)));  // 4B-aligned vec4 (out rows: 95-float stride)
typedef float f4a __attribute__((ext_vector_type(4)));               // 16B-aligned vec4 (x rows are 48-float aligned)

namespace {
constexpr int T_ = 8, D_ = 24, H_ = 48, W_ = 48;
constexpr int TO = 6, DO_ = 47, HO = 95, WO = 95;
constexpr int XCS = T_ * D_ * H_ * W_;   // x channel stride   442368
constexpr int XFS = D_ * H_ * W_;        // x frame stride      55296
constexpr int XDS = H_ * W_;             // x depth stride       2304
constexpr long OCS = (long)TO * DO_ * HO * WO;  // out channel stride 2545050
constexpr int OFS = DO_ * HO * WO;       // out frame stride   424175
constexpr int ODS = HO * WO;             // out depth stride     9025

__global__ __launch_bounds__(192) void convt4d_kernel(
    const float* __restrict__ x, const float* __restrict__ w,
    float* __restrict__ out)
{
  const int t  = threadIdx.x;           // 0..11, owns ow in [8t, 8t+8)
  const int yy = threadIdx.y;           // 0..15
  const int ohblk = blockIdx.x;         // 0..2 even rows, 3..5 odd rows
  const int od = blockIdx.y;            // 0..46
  const int f  = blockIdx.z;            // 0..5
  const int ph = (ohblk >= 3) ? 1 : 0;
  const int oh = 2 * ((ohblk - 3 * ph) * 16 + yy) + ph;
  if (oh >= HO) return;                 // only odd-class last block masks

  // depth taps (block-uniform)
  int nd, kd0, id0, kd1 = 0, id1 = 0;
  if ((od & 1) == 0) { nd = 1; kd0 = 1; id0 = od >> 1; }
  else               { nd = 2; kd0 = 0; id0 = (od + 1) >> 1; kd1 = 2; id1 = (od - 1) >> 1; }
  // height taps (wave-uniform: all lanes same parity class)
  int nh, kh0, ih0, kh1 = 0, ih1 = 0;
  if (ph == 0) { nh = 1; kh0 = 1; ih0 = oh >> 1; }
  else         { nh = 2; kh0 = 0; ih0 = (oh + 1) >> 1; kh1 = 2; ih1 = (oh - 1) >> 1; }

  const int iwb = 4 * t;
  const int x4off = (t < 11) ? 4 : 0;   // avoid 1-elem OOB read feeding the discarded ow=95

  float acc[8][8];                       // [co][m], ow = 8t+m
  #pragma unroll
  for (int co = 0; co < 8; ++co)
    #pragma unroll
    for (int m = 0; m < 8; ++m) acc[co][m] = 0.f;

  for (int i = 0; i < 3; ++i) {
    const int fr = f + i;
    for (int a = 0; a < nd; ++a) {
      const int kd = a ? kd1 : kd0;
      const int id = a ? id1 : id0;
      for (int b = 0; b < nh; ++b) {
        const int kh = b ? kh1 : kh0;
        const int ih = b ? ih1 : ih0;
        const int xoff = fr * XFS + id * XDS + ih * W_ + iwb;
        // force weight base into SGPR so weight reads go through s_load / K$
        const int wb0 = __builtin_amdgcn_readfirstlane(i * 27 + kd * 9 + kh * 3);
        #pragma unroll
        for (int ci = 0; ci < 8; ++ci) {
          const float* px = x + ci * XCS + xoff;
          const f4a xa = *(const f4a*)px;   // iw = 4t .. 4t+3 (16B aligned)
          const float xb = px[x4off];       // iw = 4t+4 (feeds odd m=7 via kw=0)
          #pragma unroll
          for (int co = 0; co < 8; ++co) {
            const int wb = wb0 + (ci * 8 + co) * 81;  // W[ci][co][i][kd][kh][kw]
            const float w0 = w[wb + 0];
            const float w1 = w[wb + 1];
            const float w2 = w[wb + 2];
            // even outputs m=0,2,4,6: kw=1, iw=4t+m/2
            acc[co][0] = fmaf(xa.x, w1, acc[co][0]);
            acc[co][2] = fmaf(xa.y, w1, acc[co][2]);
            acc[co][4] = fmaf(xa.z, w1, acc[co][4]);
            acc[co][6] = fmaf(xa.w, w1, acc[co][6]);
            // odd outputs m=1,3,5,7: kw=0 (iw=4t+(m+1)/2) + kw=2 (iw=4t+(m-1)/2)
            acc[co][1] = fmaf(xa.y, w0, fmaf(xa.x, w2, acc[co][1]));
            acc[co][3] = fmaf(xa.z, w0, fmaf(xa.y, w2, acc[co][3]));
            acc[co][5] = fmaf(xa.w, w0, fmaf(xa.z, w2, acc[co][5]));
            acc[co][7] = fmaf(xb,   w0, fmaf(xa.w, w2, acc[co][7]));
          }
        }
      }
    }
  }

  const long ob = (long)f * OFS + (long)od * ODS + (long)oh * HO + 8 * t;
  #pragma unroll
  for (int co = 0; co < 8; ++co) {
    float* po = out + co * OCS + ob;
    f4u lo; lo.x = acc[co][0]; lo.y = acc[co][1]; lo.z = acc[co][2]; lo.w = acc[co][3];
    *(f4u*)po = lo;
    if (t < 11) {
      f4u hi; hi.x = acc[co][4]; hi.y = acc[co][5]; hi.z = acc[co][6]; hi.w = acc[co][7];
      *(f4u*)(po + 4) = hi;
    } else {                      // ow = 88..94 only (ow=95 doesn't exist)
      po[4] = acc[co][4];
      po[5] = acc[co][5];
      po[6] = acc[co][6];
    }
  }
}
}  // namespace

extern "C" void kernel_launch(void* const* d_in, const int* in_sizes, int n_in,
                              void* d_out, int out_size, void* d_ws, size_t ws_size,
                              hipStream_t stream) {
  const float* x = (const float*)d_in[0];
  const float* w = (const float*)d_in[1];
  float* out = (float*)d_out;
  dim3 grid(6, 47, 6);     // (oh parity-blocks, od, f)
  dim3 block(12, 16, 1);   // (w-groups, oh rows within parity class)
  hipLaunchKernelGGL(convt4d_kernel, grid, block, 0, stream, x, w, out);
}